// Round 1
// baseline (1245.164 us; speedup 1.0000x reference)
//
#include <hip/hip_runtime.h>
#include <hip/hip_bf16.h>

#define B 4
#define N_ALL 8192
#define N_VOX 4096
#define S_PTS 1024
#define K_SAMPLE 32
#define R2 0.04f

// ---------------------------------------------------------------------------
// Kernel 1: FPS (farthest point sampling) + gather of new_xyz / new_normals.
// One block per batch. 256 threads, 16 points/thread held in registers.
// All 4096 points staged in LDS so any thread can read xyz[last] directly.
// Matches jnp.argmax tie-break (first/lowest index) and fp32 arithmetic
// order (dx*dx + dy*dy) + dz*dz with no FMA contraction.
// ---------------------------------------------------------------------------
__global__ __launch_bounds__(256) void fps_gather_kernel(
    const float* __restrict__ xyz_voxel,
    const float* __restrict__ normals_voxel,
    float* __restrict__ out_xyz,      // (B, S, 3)
    float* __restrict__ out_normals)  // (B, S, 3)
{
    const int b = blockIdx.x;
    const int t = threadIdx.x;
    const int wid = t >> 6;
    const int lane = t & 63;

    __shared__ float sx[N_VOX], sy[N_VOX], sz[N_VOX];
    __shared__ int   fps_lds[S_PTS];
    __shared__ float s_pval[2][4];
    __shared__ int   s_pidx[2][4];

    const float* xyz = xyz_voxel + (size_t)b * N_VOX * 3;

    for (int i = t; i < N_VOX; i += 256) {
        sx[i] = xyz[i * 3 + 0];
        sy[i] = xyz[i * 3 + 1];
        sz[i] = xyz[i * 3 + 2];
    }
    __syncthreads();

    // Per-thread points: thread t owns indices t, t+256, ..., t+3840.
    float px[16], py[16], pz[16], dist[16];
#pragma unroll
    for (int j = 0; j < 16; j++) {
        int i = t + j * 256;
        px[j] = sx[i]; py[j] = sy[i]; pz[j] = sz[i];
        dist[j] = 1e10f;
    }

    if (t == 0) fps_lds[0] = 0;
    float lx = sx[0], ly = sy[0], lz = sz[0];

    for (int step = 1; step < S_PTS; step++) {
        // Update min-distances and find thread-local argmax (lowest idx on tie;
        // local indices ascend with j so strict > preserves first-occurrence).
        float bestv = -1.0f; int besti = 0;
#pragma unroll
        for (int j = 0; j < 16; j++) {
            float dx = __fsub_rn(px[j], lx);
            float dy = __fsub_rn(py[j], ly);
            float dz = __fsub_rn(pz[j], lz);
            float d  = __fadd_rn(__fadd_rn(__fmul_rn(dx, dx), __fmul_rn(dy, dy)),
                                 __fmul_rn(dz, dz));
            float dm = fminf(dist[j], d);
            dist[j] = dm;
            int gi = t + j * 256;
            if (dm > bestv) { bestv = dm; besti = gi; }
        }
        // Wave argmax (64 lanes), tie-break lowest global index.
#pragma unroll
        for (int off = 32; off >= 1; off >>= 1) {
            float ov = __shfl_down(bestv, off, 64);
            int   oi = __shfl_down(besti, off, 64);
            if (ov > bestv || (ov == bestv && oi < besti)) { bestv = ov; besti = oi; }
        }
        const int buf = step & 1;
        if (lane == 0) { s_pval[buf][wid] = bestv; s_pidx[buf][wid] = besti; }
        __syncthreads();
        // All threads redundantly reduce the 4 wave partials -> same 'last'.
        bestv = s_pval[buf][0]; besti = s_pidx[buf][0];
#pragma unroll
        for (int w = 1; w < 4; w++) {
            float ov = s_pval[buf][w]; int oi = s_pidx[buf][w];
            if (ov > bestv || (ov == bestv && oi < besti)) { bestv = ov; besti = oi; }
        }
        lx = sx[besti]; ly = sy[besti]; lz = sz[besti];
        if (t == 0) fps_lds[step] = besti;
        // Double-buffered partials: next step writes buf^1, so no second barrier.
    }
    __syncthreads();

    // Gather new_xyz from LDS copy, new_normals from global.
    for (int i = t; i < S_PTS; i += 256) {
        int idx = fps_lds[i];
        int o = (b * S_PTS + i) * 3;
        out_xyz[o + 0] = sx[idx];
        out_xyz[o + 1] = sy[idx];
        out_xyz[o + 2] = sz[idx];
        const float* nv = normals_voxel + ((size_t)b * N_VOX + idx) * 3;
        out_normals[o + 0] = nv[0];
        out_normals[o + 1] = nv[1];
        out_normals[o + 2] = nv[2];
    }
}

// ---------------------------------------------------------------------------
// Kernel 2: ball query + grouping. One wave per query point (B*S = 4096 waves,
// 4 waves/block -> 1024 blocks). Scans candidates in ascending index order via
// 64-wide ballot + prefix popcount, collecting the first 32 hits — exactly
// reproducing sort(where(d2 < r2, arange, N))[:32] with pad-by-first.
// d2 uses the reference's expanded form (qq + pp) - 2*dot, no FMA contraction.
// ---------------------------------------------------------------------------
__global__ __launch_bounds__(256) void ballquery_group_kernel(
    const float* __restrict__ xyz_all,   // (B, N_ALL, 3)
    const float* __restrict__ normals,   // (B, N_ALL, 3)
    const float* __restrict__ new_xyz,   // (B, S, 3)  -- out1
    float* __restrict__ out_feat,        // (B, 3, S, K)
    float* __restrict__ out_featn)       // (B, 6, S, K)
{
    const int wid = threadIdx.x >> 6;
    const int lane = threadIdx.x & 63;
    const int q = blockIdx.x * 4 + wid;        // 0..4095
    const int b = q >> 10;
    const int s = q & 1023;

    const float* xyz = xyz_all + (size_t)b * N_ALL * 3;
    const float* nrm = normals + (size_t)b * N_ALL * 3;

    const float qx = new_xyz[q * 3 + 0];
    const float qy = new_xyz[q * 3 + 1];
    const float qz = new_xyz[q * 3 + 2];
    const float qq = __fadd_rn(__fadd_rn(__fmul_rn(qx, qx), __fmul_rn(qy, qy)),
                               __fmul_rn(qz, qz));

    __shared__ int sidx[4][K_SAMPLE];

    int cnt = 0;
    for (int c = 0; c < N_ALL / 64 && cnt < K_SAMPLE; c++) {
        int i = c * 64 + lane;
        float px = xyz[i * 3 + 0];
        float py = xyz[i * 3 + 1];
        float pz = xyz[i * 3 + 2];
        float pp = __fadd_rn(__fadd_rn(__fmul_rn(px, px), __fmul_rn(py, py)),
                             __fmul_rn(pz, pz));
        float dt = __fadd_rn(__fadd_rn(__fmul_rn(qx, px), __fmul_rn(qy, py)),
                             __fmul_rn(qz, pz));
        float d2 = __fsub_rn(__fadd_rn(qq, pp), __fmul_rn(2.0f, dt));
        bool hit = d2 < R2;
        unsigned long long mask = __ballot(hit);
        if (hit) {
            int pos = cnt + __popcll(mask & ((1ull << lane) - 1ull));
            if (pos < K_SAMPLE) sidx[wid][pos] = i;
        }
        cnt += (int)__popcll(mask);
    }
    __syncthreads();  // LDS visibility (all threads reach exactly once)

    if (lane < K_SAMPLE) {
        int idxj;
        if (cnt == 0)            idxj = 0;                 // no hits -> index 0
        else if (lane < cnt)     idxj = sidx[wid][lane];
        else                     idxj = sidx[wid][0];      // pad with first hit

        float px = xyz[idxj * 3 + 0];
        float py = xyz[idxj * 3 + 1];
        float pz = xyz[idxj * 3 + 2];
        float rx = __fsub_rn(px, qx);
        float ry = __fsub_rn(py, qy);
        float rz = __fsub_rn(pz, qz);

        // out_feat[b][c][s][j], channel stride = S*K = 32768
        int o3 = ((b * 3) * S_PTS + s) * K_SAMPLE + lane;
        out_feat[o3 + 0 * 32768] = rx;
        out_feat[o3 + 1 * 32768] = ry;
        out_feat[o3 + 2 * 32768] = rz;

        float nx = nrm[idxj * 3 + 0];
        float ny = nrm[idxj * 3 + 1];
        float nz = nrm[idxj * 3 + 2];

        // out_featn[b][c][s][j], channel stride = 32768, 6 channels per batch
        int o4 = ((b * 6) * S_PTS + s) * K_SAMPLE + lane;
        out_featn[o4 + 0 * 32768] = rx;
        out_featn[o4 + 1 * 32768] = ry;
        out_featn[o4 + 2 * 32768] = rz;
        out_featn[o4 + 3 * 32768] = nx;
        out_featn[o4 + 4 * 32768] = ny;
        out_featn[o4 + 5 * 32768] = nz;
    }
}

extern "C" void kernel_launch(void* const* d_in, const int* in_sizes, int n_in,
                              void* d_out, int out_size, void* d_ws, size_t ws_size,
                              hipStream_t stream) {
    const float* xyz_all       = (const float*)d_in[0];  // (4, 8192, 3)
    const float* normals       = (const float*)d_in[1];  // (4, 8192, 3)
    const float* xyz_voxel     = (const float*)d_in[2];  // (4, 4096, 3)
    const float* normals_voxel = (const float*)d_in[3];  // (4, 4096, 3)

    float* out = (float*)d_out;
    float* out_xyz     = out;                    // (4, 1024, 3)    = 12288
    float* out_normals = out + 12288;            // (4, 1024, 3)    = 12288
    float* out_feat    = out + 24576;            // (4, 3, 1024, 32)= 393216
    float* out_featn   = out + 417792;           // (4, 6, 1024, 32)= 786432

    fps_gather_kernel<<<B, 256, 0, stream>>>(xyz_voxel, normals_voxel,
                                             out_xyz, out_normals);
    ballquery_group_kernel<<<(B * S_PTS) / 4, 256, 0, stream>>>(
        xyz_all, normals, out_xyz, out_feat, out_featn);
}

// Round 2
// 727.642 us; speedup vs baseline: 1.7112x; 1.7112x over previous
//
#include <hip/hip_runtime.h>
#include <hip/hip_bf16.h>

#define B 4
#define N_ALL 8192
#define N_VOX 4096
#define S_PTS 1024
#define K_SAMPLE 32
#define R2 0.04f

#define FPS_T 512                 // threads per FPS block (8 waves)
#define PPT (N_VOX / FPS_T)       // 8 points per thread
#define PREP_BLOCKS ((B * N_ALL) / FPS_T)   // 64 blocks for the packed-xyz prep

__device__ __forceinline__ unsigned long long key_max(unsigned long long a,
                                                      unsigned long long b) {
    return a > b ? a : b;
}

// Wave64 max-reduction via DPP (VALU latency, no LDS). Result valid in lane 63.
// Keys are >= 0 so identity 0 is safe for invalid-source lanes (old = 0).
__device__ __forceinline__ unsigned long long wave_key_max(unsigned long long k) {
#define DPP_RED(ctrl)                                                              \
    {                                                                              \
        unsigned int lo = (unsigned int)k;                                         \
        unsigned int hi = (unsigned int)(k >> 32);                                 \
        unsigned int nlo =                                                         \
            (unsigned int)__builtin_amdgcn_update_dpp(0, (int)lo, ctrl, 0xf, 0xf, false); \
        unsigned int nhi =                                                         \
            (unsigned int)__builtin_amdgcn_update_dpp(0, (int)hi, ctrl, 0xf, 0xf, false); \
        unsigned long long nk = ((unsigned long long)nhi << 32) | nlo;             \
        if (nk > k) k = nk;                                                        \
    }
    DPP_RED(0x111);  // row_shr:1
    DPP_RED(0x112);  // row_shr:2
    DPP_RED(0x114);  // row_shr:4
    DPP_RED(0x118);  // row_shr:8   -> lane 15/31/47/63 hold row reductions
    DPP_RED(0x142);  // row_bcast:15 -> lane 31 = rows01, lane 63 = rows23
    DPP_RED(0x143);  // row_bcast:31 -> lane 63 = all 64 lanes
#undef DPP_RED
    return k;
}

// ---------------------------------------------------------------------------
// Kernel 1: blocks 0..3 run FPS (one block per batch); blocks 4.. pack
// (x, y, z, ||p||^2) of xyz_all into d_ws for the ball-query kernel.
// FPS: 512 threads, 8 pts/thread in registers, u64 (dist-bits | ~idx) keys,
// DPP wave reduce, single barrier per iteration (double-buffered partials).
// Exact fp32 op order matches the JAX reference (no FMA contraction).
// ---------------------------------------------------------------------------
__global__ __launch_bounds__(FPS_T) void fps_prep_kernel(
    const float* __restrict__ xyz_voxel,
    const float* __restrict__ normals_voxel,
    const float* __restrict__ xyz_all,
    float* __restrict__ out_xyz,      // (B, S, 3)
    float* __restrict__ out_normals,  // (B, S, 3)
    float4* __restrict__ ws_packed,   // (B, N_ALL) {x,y,z,pp}; may be unused
    int do_prep)
{
    if (blockIdx.x >= B) {
        // ---- prep role: pack xyz_all + squared norm into workspace ----
        if (!do_prep) return;
        int pid = (blockIdx.x - B) * FPS_T + threadIdx.x;
        if (pid < B * N_ALL) {
            float x = xyz_all[pid * 3 + 0];
            float y = xyz_all[pid * 3 + 1];
            float z = xyz_all[pid * 3 + 2];
            float pp = __fadd_rn(__fadd_rn(__fmul_rn(x, x), __fmul_rn(y, y)),
                                 __fmul_rn(z, z));
            ws_packed[pid] = make_float4(x, y, z, pp);
        }
        return;
    }

    // ---- FPS role ----
    const int b = blockIdx.x;
    const int t = threadIdx.x;
    const int wid = t >> 6;    // 0..7
    const int lane = t & 63;

    __shared__ float4 sp[N_VOX];                       // 64 KB, b128 broadcast reads
    __shared__ int fps_idx_s[S_PTS];
    __shared__ unsigned long long s_part[2][FPS_T / 64];

    const float* xyz = xyz_voxel + (size_t)b * N_VOX * 3;
    for (int i = t; i < N_VOX; i += FPS_T) {
        float x = xyz[i * 3 + 0];
        float y = xyz[i * 3 + 1];
        float z = xyz[i * 3 + 2];
        sp[i] = make_float4(x, y, z, 0.0f);
    }
    __syncthreads();

    // Thread t owns points t, t+512, ..., t+3584 (all register-resident).
    float px[PPT], py[PPT], pz[PPT], dist[PPT];
    unsigned int ilo[PPT];
#pragma unroll
    for (int j = 0; j < PPT; j++) {
        float4 c = sp[t + j * FPS_T];
        px[j] = c.x; py[j] = c.y; pz[j] = c.z;
        dist[j] = 1e10f;
        ilo[j] = ~(unsigned int)(t + j * FPS_T);   // tie-break: max(~i) = min(i)
    }

    if (t == 0) fps_idx_s[0] = 0;
    float4 c0 = sp[0];
    float lx = c0.x, ly = c0.y, lz = c0.z;

    for (int step = 1; step < S_PTS; step++) {
        unsigned long long k[PPT];
#pragma unroll
        for (int j = 0; j < PPT; j++) {
            float dx = __fsub_rn(px[j], lx);
            float dy = __fsub_rn(py[j], ly);
            float dz = __fsub_rn(pz[j], lz);
            float d  = __fadd_rn(__fadd_rn(__fmul_rn(dx, dx), __fmul_rn(dy, dy)),
                                 __fmul_rn(dz, dz));
            float dm = fminf(dist[j], d);
            dist[j] = dm;
            // dist >= 0 so fp32 bits are monotone as unsigned; key max ==
            // argmax with lowest-index tie-break (jnp.argmax semantics).
            k[j] = ((unsigned long long)__float_as_uint(dm) << 32) | ilo[j];
        }
        // Local tree reduce (depth 3).
        unsigned long long a0 = key_max(k[0], k[1]);
        unsigned long long a1 = key_max(k[2], k[3]);
        unsigned long long a2 = key_max(k[4], k[5]);
        unsigned long long a3 = key_max(k[6], k[7]);
        a0 = key_max(a0, a1);
        a2 = key_max(a2, a3);
        a0 = key_max(a0, a2);
        // Wave reduce via DPP (result in lane 63).
        a0 = wave_key_max(a0);

        const int buf = step & 1;
        if (lane == 63) s_part[buf][wid] = a0;
        __syncthreads();
        // All threads redundantly reduce the 8 wave partials -> same winner.
        unsigned long long p0 = key_max(s_part[buf][0], s_part[buf][1]);
        unsigned long long p1 = key_max(s_part[buf][2], s_part[buf][3]);
        unsigned long long p2 = key_max(s_part[buf][4], s_part[buf][5]);
        unsigned long long p3 = key_max(s_part[buf][6], s_part[buf][7]);
        p0 = key_max(p0, p1);
        p2 = key_max(p2, p3);
        p0 = key_max(p0, p2);
        int besti = (int)(~(unsigned int)p0);
        float4 cb = sp[besti];             // single b128 broadcast read
        lx = cb.x; ly = cb.y; lz = cb.z;
        if (t == 0) fps_idx_s[step] = besti;
        // Double-buffered partials: next iter writes buf^1 -> one barrier/iter.
    }
    __syncthreads();

    // Gather new_xyz / new_normals.
    for (int i = t; i < S_PTS; i += FPS_T) {
        int idx = fps_idx_s[i];
        int o = (b * S_PTS + i) * 3;
        float4 c = sp[idx];
        out_xyz[o + 0] = c.x;
        out_xyz[o + 1] = c.y;
        out_xyz[o + 2] = c.z;
        const float* nv = normals_voxel + ((size_t)b * N_VOX + idx) * 3;
        out_normals[o + 0] = nv[0];
        out_normals[o + 1] = nv[1];
        out_normals[o + 2] = nv[2];
    }
}

// ---------------------------------------------------------------------------
// Kernel 2: ball query + grouping. One wave per query point, ballot + prefix
// popcount collects the first 32 hits in index order (== sorted where()).
// PACKED: candidates come as coalesced float4 {x,y,z,pp} from d_ws.
// ---------------------------------------------------------------------------
template <bool PACKED>
__global__ __launch_bounds__(256) void ballquery_group_kernel(
    const float* __restrict__ xyz_all,   // (B, N_ALL, 3)
    const float* __restrict__ normals,   // (B, N_ALL, 3)
    const float* __restrict__ new_xyz,   // (B, S, 3)  -- out1
    const float4* __restrict__ pw,       // (B, N_ALL) packed, if PACKED
    float* __restrict__ out_feat,        // (B, 3, S, K)
    float* __restrict__ out_featn)       // (B, 6, S, K)
{
    const int wid = threadIdx.x >> 6;
    const int lane = threadIdx.x & 63;
    const int q = blockIdx.x * 4 + wid;        // 0..4095
    const int b = q >> 10;
    const int s = q & 1023;

    const float* xyz = xyz_all + (size_t)b * N_ALL * 3;
    const float* nrm = normals + (size_t)b * N_ALL * 3;
    const float4* pwb = PACKED ? (pw + (size_t)b * N_ALL) : nullptr;

    const float qx = new_xyz[q * 3 + 0];
    const float qy = new_xyz[q * 3 + 1];
    const float qz = new_xyz[q * 3 + 2];
    const float qq = __fadd_rn(__fadd_rn(__fmul_rn(qx, qx), __fmul_rn(qy, qy)),
                               __fmul_rn(qz, qz));

    __shared__ int sidx[4][K_SAMPLE];

    int cnt = 0;
    for (int c = 0; c < N_ALL / 64 && cnt < K_SAMPLE; c++) {
        int i = c * 64 + lane;
        float px, py, pz, pp;
        if (PACKED) {
            float4 cc = pwb[i];
            px = cc.x; py = cc.y; pz = cc.z; pp = cc.w;
        } else {
            px = xyz[i * 3 + 0];
            py = xyz[i * 3 + 1];
            pz = xyz[i * 3 + 2];
            pp = __fadd_rn(__fadd_rn(__fmul_rn(px, px), __fmul_rn(py, py)),
                           __fmul_rn(pz, pz));
        }
        float dt = __fadd_rn(__fadd_rn(__fmul_rn(qx, px), __fmul_rn(qy, py)),
                             __fmul_rn(qz, pz));
        float d2 = __fsub_rn(__fadd_rn(qq, pp), __fmul_rn(2.0f, dt));
        bool hit = d2 < R2;
        unsigned long long mask = __ballot(hit);
        if (hit) {
            int pos = cnt + __popcll(mask & ((1ull << lane) - 1ull));
            if (pos < K_SAMPLE) sidx[wid][pos] = i;
        }
        cnt += (int)__popcll(mask);
    }
    __syncthreads();  // all threads reach exactly once

    if (lane < K_SAMPLE) {
        int idxj;
        if (cnt == 0)        idxj = 0;              // no hits -> index 0
        else if (lane < cnt) idxj = sidx[wid][lane];
        else                 idxj = sidx[wid][0];   // pad with first hit

        float px, py, pz;
        if (PACKED) {
            float4 cc = pwb[idxj];
            px = cc.x; py = cc.y; pz = cc.z;
        } else {
            px = xyz[idxj * 3 + 0];
            py = xyz[idxj * 3 + 1];
            pz = xyz[idxj * 3 + 2];
        }
        float rx = __fsub_rn(px, qx);
        float ry = __fsub_rn(py, qy);
        float rz = __fsub_rn(pz, qz);

        int o3 = ((b * 3) * S_PTS + s) * K_SAMPLE + lane;   // chan stride 32768
        out_feat[o3 + 0 * 32768] = rx;
        out_feat[o3 + 1 * 32768] = ry;
        out_feat[o3 + 2 * 32768] = rz;

        float nx = nrm[idxj * 3 + 0];
        float ny = nrm[idxj * 3 + 1];
        float nz = nrm[idxj * 3 + 2];

        int o4 = ((b * 6) * S_PTS + s) * K_SAMPLE + lane;
        out_featn[o4 + 0 * 32768] = rx;
        out_featn[o4 + 1 * 32768] = ry;
        out_featn[o4 + 2 * 32768] = rz;
        out_featn[o4 + 3 * 32768] = nx;
        out_featn[o4 + 4 * 32768] = ny;
        out_featn[o4 + 5 * 32768] = nz;
    }
}

extern "C" void kernel_launch(void* const* d_in, const int* in_sizes, int n_in,
                              void* d_out, int out_size, void* d_ws, size_t ws_size,
                              hipStream_t stream) {
    const float* xyz_all       = (const float*)d_in[0];  // (4, 8192, 3)
    const float* normals       = (const float*)d_in[1];  // (4, 8192, 3)
    const float* xyz_voxel     = (const float*)d_in[2];  // (4, 4096, 3)
    const float* normals_voxel = (const float*)d_in[3];  // (4, 4096, 3)

    float* out = (float*)d_out;
    float* out_xyz     = out;           // (4, 1024, 3)     = 12288
    float* out_normals = out + 12288;   // (4, 1024, 3)     = 12288
    float* out_feat    = out + 24576;   // (4, 3, 1024, 32) = 393216
    float* out_featn   = out + 417792;  // (4, 6, 1024, 32) = 786432

    const size_t need = (size_t)B * N_ALL * sizeof(float4);   // 512 KB
    const bool use_ws = ws_size >= need;

    fps_prep_kernel<<<B + (use_ws ? PREP_BLOCKS : 0), FPS_T, 0, stream>>>(
        xyz_voxel, normals_voxel, xyz_all, out_xyz, out_normals,
        (float4*)d_ws, use_ws ? 1 : 0);

    if (use_ws) {
        ballquery_group_kernel<true><<<(B * S_PTS) / 4, 256, 0, stream>>>(
            xyz_all, normals, out_xyz, (const float4*)d_ws, out_feat, out_featn);
    } else {
        ballquery_group_kernel<false><<<(B * S_PTS) / 4, 256, 0, stream>>>(
            xyz_all, normals, out_xyz, nullptr, out_feat, out_featn);
    }
}